// Round 7
// baseline (1058.653 us; speedup 1.0000x reference)
//
#include <hip/hip_runtime.h>

typedef signed char char8v __attribute__((ext_vector_type(8)));
typedef signed char char4v __attribute__((ext_vector_type(4)));
typedef short short8 __attribute__((ext_vector_type(8)));
typedef int int32x4 __attribute__((ext_vector_type(4)));

static constexpr int DM = 2048;   // d_model
static constexpr int DF = 8192;   // d_ff
static constexpr int MT = 8192;   // B*S tokens
static constexpr int CH = 4096;   // M-chunk for stage 2
static constexpr float INVN = 1.0f / 16777216.0f;  // 1/(DF*DM)

// workspace layout (bytes); total ~184MB
static constexpr size_t OFF_STATS = 256;                           // 8192*2 f32
static constexpr size_t OFF_QX   = OFF_STATS + 65536;              // i8 [MT][DM]    16MB
static constexpr size_t OFF_QW1  = OFF_QX  + (size_t)MT * DM;      // i8 [DF][DM]    16MB
static constexpr size_t OFF_QW2  = OFF_QW1 + (size_t)DF * DM;      // i8 [DM][DF]    16MB
static constexpr size_t OFF_HACC = OFF_QW2 + (size_t)DM * DF;      // i16 [MT][DF]  128MB
// qh chunk (i8 [CH][DF] = 32MB) reuses [OFF_QX, OFF_QX+32MB) after GEMM1 (qx+qw1 dead).

__device__ __forceinline__ float waveSum(float v) {
#pragma unroll
  for (int o = 32; o > 0; o >>= 1) v += __shfl_xor(v, o, 64);
  return v;
}
__device__ __forceinline__ float waveMax(float v) {
#pragma unroll
  for (int o = 32; o > 0; o >>= 1) v = fmaxf(v, __shfl_xor(v, o, 64));
  return v;
}
__device__ __forceinline__ float gelu_exact(float v) {
  return 0.5f * v * (1.0f + erff(v * 0.70710678118654752f));
}
__device__ __forceinline__ signed char q8(float v, float lo, float hi) {
  return (signed char)fminf(fmaxf(rintf(v), lo), hi);
}

__global__ __launch_bounds__(64) void zero_k(float* p) { p[threadIdx.x] = 0.f; }

// ---------------- sum(|w|) reduction ----------------
__global__ __launch_bounds__(256) void abssum_k(const float4* __restrict__ w, int n4,
                                                float* __restrict__ out) {
  float s = 0.f;
  for (int i = blockIdx.x * 256 + threadIdx.x; i < n4; i += gridDim.x * 256) {
    float4 v = w[i];
    s += fabsf(v.x) + fabsf(v.y) + fabsf(v.z) + fabsf(v.w);
  }
  s = waveSum(s);
  __shared__ float sm[4];
  if ((threadIdx.x & 63) == 0) sm[threadIdx.x >> 6] = s;
  __syncthreads();
  if (threadIdx.x == 0) atomicAdd(out, sm[0] + sm[1] + sm[2] + sm[3]);
}

// ---------------- layernorm stats + global absmax(x_ln) ----------------
__global__ __launch_bounds__(256) void ln_k(const float* __restrict__ x, const float* __restrict__ w,
                                            const float* __restrict__ b, float* __restrict__ stats,
                                            unsigned* __restrict__ amax) {
  __shared__ float sm[4];
  const int row = blockIdx.x, t = threadIdx.x;
  const float4* xr = (const float4*)(x + (size_t)row * DM);
  float4 v0 = xr[t], v1 = xr[t + 256];
  float s = v0.x + v0.y + v0.z + v0.w + v1.x + v1.y + v1.z + v1.w;
  s = waveSum(s);
  if ((t & 63) == 0) sm[t >> 6] = s;
  __syncthreads();
  const float mu = (sm[0] + sm[1] + sm[2] + sm[3]) * (1.0f / DM);
  __syncthreads();
  float d[8] = {v0.x - mu, v0.y - mu, v0.z - mu, v0.w - mu,
                v1.x - mu, v1.y - mu, v1.z - mu, v1.w - mu};
  float sq = 0.f;
#pragma unroll
  for (int i = 0; i < 8; i++) sq += d[i] * d[i];
  sq = waveSum(sq);
  if ((t & 63) == 0) sm[t >> 6] = sq;
  __syncthreads();
  const float var = (sm[0] + sm[1] + sm[2] + sm[3]) * (1.0f / DM);
  const float rstd = 1.0f / sqrtf(var + 1e-5f);
  __syncthreads();
  const float4* wr = (const float4*)w;
  const float4* br = (const float4*)b;
  float4 w0 = wr[t], w1v = wr[t + 256], b0 = br[t], b1v = br[t + 256];
  float m = 0.f;
  m = fmaxf(m, fabsf(d[0] * rstd * w0.x + b0.x));
  m = fmaxf(m, fabsf(d[1] * rstd * w0.y + b0.y));
  m = fmaxf(m, fabsf(d[2] * rstd * w0.z + b0.z));
  m = fmaxf(m, fabsf(d[3] * rstd * w0.w + b0.w));
  m = fmaxf(m, fabsf(d[4] * rstd * w1v.x + b1v.x));
  m = fmaxf(m, fabsf(d[5] * rstd * w1v.y + b1v.y));
  m = fmaxf(m, fabsf(d[6] * rstd * w1v.z + b1v.z));
  m = fmaxf(m, fabsf(d[7] * rstd * w1v.w + b1v.w));
  m = waveMax(m);
  if ((t & 63) == 0) sm[t >> 6] = m;
  __syncthreads();
  if (t == 0) {
    float mm = fmaxf(fmaxf(sm[0], sm[1]), fmaxf(sm[2], sm[3]));
    stats[2 * row] = mu;
    stats[2 * row + 1] = rstd;
    atomicMax(amax, __float_as_uint(mm));
  }
}

// ---------------- quantize activations -> int8 ----------------
__global__ __launch_bounds__(256) void quantx_k(const float* __restrict__ x, const float* __restrict__ w,
                                                const float* __restrict__ b, const float* __restrict__ stats,
                                                const float* __restrict__ scal, signed char* __restrict__ qx) {
  const int row = blockIdx.x, t = threadIdx.x;
  const float mu = stats[2 * row], rstd = stats[2 * row + 1];
  const float sc = 127.0f / fmaxf(scal[2], 1e-5f);
  const float4* xr = (const float4*)(x + (size_t)row * DM);
  const float4* wr = (const float4*)w;
  const float4* br = (const float4*)b;
  float4 v0 = xr[2 * t], v1 = xr[2 * t + 1];
  float4 w0 = wr[2 * t], w1v = wr[2 * t + 1];
  float4 b0 = br[2 * t], b1v = br[2 * t + 1];
  char8v o;
  o[0] = q8(((v0.x - mu) * rstd * w0.x + b0.x) * sc, -127.f, 127.f);
  o[1] = q8(((v0.y - mu) * rstd * w0.y + b0.y) * sc, -127.f, 127.f);
  o[2] = q8(((v0.z - mu) * rstd * w0.z + b0.z) * sc, -127.f, 127.f);
  o[3] = q8(((v0.w - mu) * rstd * w0.w + b0.w) * sc, -127.f, 127.f);
  o[4] = q8(((v1.x - mu) * rstd * w1v.x + b1v.x) * sc, -127.f, 127.f);
  o[5] = q8(((v1.y - mu) * rstd * w1v.y + b1v.y) * sc, -127.f, 127.f);
  o[6] = q8(((v1.z - mu) * rstd * w1v.z + b1v.z) * sc, -127.f, 127.f);
  o[7] = q8(((v1.w - mu) * rstd * w1v.w + b1v.w) * sc, -127.f, 127.f);
  *(char8v*)(qx + (size_t)row * DM + t * 8) = o;
}

// ---------------- ternarize weights -> int8 ----------------
__global__ __launch_bounds__(256) void quantw_k(const float4* __restrict__ w, const float* __restrict__ sumabs,
                                                signed char* __restrict__ qw, int n4) {
  const float beta = fmaxf(*sumabs * INVN, 1e-5f);
  const float rb = 1.0f / beta;
  for (int i = blockIdx.x * 256 + threadIdx.x; i < n4; i += gridDim.x * 256) {
    float4 v = w[i];
    char4v o;
    o[0] = q8(v.x * rb, -1.f, 1.f);
    o[1] = q8(v.y * rb, -1.f, 1.f);
    o[2] = q8(v.z * rb, -1.f, 1.f);
    o[3] = q8(v.w * rb, -1.f, 1.f);
    *(char4v*)(qw + (size_t)i * 4) = o;
  }
}

// ---------------- quantize h chunk: gelu(s1*acc) -> int8 ----------------
__global__ __launch_bounds__(256) void quanth_k(const short8* __restrict__ hacc,
                                                const float* __restrict__ scal,
                                                signed char* __restrict__ qh, int n8) {
  const float s1 = fmaxf(scal[0] * INVN, 1e-5f) * fmaxf(scal[2], 1e-5f) * (1.0f / 127.0f);
  const float sc2 = 127.0f / fmaxf(scal[3], 1e-5f);
  for (int i = blockIdx.x * 256 + threadIdx.x; i < n8; i += gridDim.x * 256) {
    short8 v = hacc[i];
    char8v o;
#pragma unroll
    for (int j = 0; j < 8; j++) {
      const float g = gelu_exact((float)v[j] * s1);
      o[j] = q8(g * sc2, -127.f, 127.f);
    }
    *(char8v*)(qh + (size_t)i * 8) = o;
  }
}

// ---------------- GEMM: C[M][N] = A[M][K] * B[N][K]^T, exact int8 MFMA ----------------
// EPI=1: store raw acc as int16 (LDS-coalesced) + amax(gelu(acc*s)); EPI=0: store f32 acc*s
__device__ __forceinline__ void gll16(const signed char* g, signed char* l) {
  __builtin_amdgcn_global_load_lds((const __attribute__((address_space(1))) void*)g,
                                   (__attribute__((address_space(3))) void*)l, 16, 0, 0);
}

template <int EPI>
__global__ __launch_bounds__(256, 4) void gemm_i8(const signed char* __restrict__ A,
                                                  const signed char* __restrict__ B,
                                                  void* __restrict__ Cv, int M, int N, int K, int nbx,
                                                  const float* __restrict__ p_sumw,
                                                  const float* __restrict__ p_amax,
                                                  unsigned* __restrict__ amax_out) {
  // union: [0,8K) As, [8K,16K) Bs during K-loop; 4 x 9216B per-wave C-stage in epilogue
  __shared__ __align__(16) char smem[36864];
  signed char* As = (signed char*)smem;
  signed char* Bs = (signed char*)smem + 8192;
  const int tid = threadIdx.x;
  const int wid = tid >> 6, lane = tid & 63;

  // bijective XCD swizzle (nwg % 8 == 0 for all our grids)
  const int nwg = gridDim.x;
  const int qc = nwg >> 3;
  const int swz = ((int)blockIdx.x & 7) * qc + ((int)blockIdx.x >> 3);
  const int bx = swz % nbx, by = swz / nbx;
  const int m0 = by * 128, n0 = bx * 128;
  const int wm = (wid >> 1) * 64, wn = (wid & 1) * 64;

  int32x4 acc[4][4];
#pragma unroll
  for (int i = 0; i < 4; i++)
#pragma unroll
    for (int j = 0; j < 4; j++) acc[i][j] = int32x4{0, 0, 0, 0};

  // staging: thread t -> row t/4 (+64 on 2nd issue), byte-col (t&3)*16
  const int srow = tid >> 2;
  const int scol = (tid & 3) * 16;
  const signed char* gA = A + (size_t)(m0 + srow) * K + scol;
  const signed char* gB = B + (size_t)(n0 + srow) * K + scol;
  const size_t rowK64 = (size_t)64 * K;

  // fragment LDS byte offsets: lane = 16q + r -> row r, k-bytes [16q,16q+16)
  const int lrow = lane & 15;
  const int lkb = (lane >> 4) * 16;
  const int aoff = (wm + lrow) * 64 + lkb;
  const int boff = (wn + lrow) * 64 + lkb;

  for (int k0 = 0; k0 < K; k0 += 64) {
    __syncthreads();
    gll16(gA + k0,          As + wid * 1024);
    gll16(gA + k0 + rowK64, As + 4096 + wid * 1024);
    gll16(gB + k0,          Bs + wid * 1024);
    gll16(gB + k0 + rowK64, Bs + 4096 + wid * 1024);
    __syncthreads();

    int32x4 af[4], bfv[4];
#pragma unroll
    for (int m = 0; m < 4; m++) af[m] = *(const int32x4*)(As + aoff + m * 1024);
#pragma unroll
    for (int n = 0; n < 4; n++) bfv[n] = *(const int32x4*)(Bs + boff + n * 1024);
#pragma unroll
    for (int m = 0; m < 4; m++)
#pragma unroll
      for (int n = 0; n < 4; n++)
        acc[m][n] = __builtin_amdgcn_mfma_i32_16x16x64_i8(af[m], bfv[n], acc[m][n], 0, 0, 0);
  }

  const float beta = fmaxf(p_sumw[0] * INVN, 1e-5f);
  const float s = beta * fmaxf(p_amax[0], 1e-5f) * (1.0f / 127.0f);
  const int q = lane >> 4, r = lane & 15;

  if (EPI == 1) {
    float lmax = 0.f;
#pragma unroll
    for (int m = 0; m < 4; m++)
#pragma unroll
      for (int n = 0; n < 4; n++)
#pragma unroll
        for (int j = 0; j < 4; j++)
          lmax = fmaxf(lmax, fabsf(gelu_exact((float)acc[m][n][j] * s)));
    lmax = waveMax(lmax);
    if (lane == 0) atomicMax(amax_out, __float_as_uint(lmax));
  }

  __syncthreads();  // all waves done reading As/Bs; safe to reuse smem for C-staging

  if (EPI == 1) {
    // stage int16 64x64 tile (rows padded to 72 shorts = 144B, 16B-aligned)
    short* Cs = (short*)(smem + wid * 9216);
#pragma unroll
    for (int m = 0; m < 4; m++)
#pragma unroll
      for (int n = 0; n < 4; n++)
#pragma unroll
        for (int j = 0; j < 4; j++)
          Cs[(m * 16 + q * 4 + j) * 72 + n * 16 + r] =
              (short)fminf(fmaxf((float)acc[m][n][j], -32767.f), 32767.f);
    const int orow = lane >> 3, oc8 = (lane & 7) * 8;
    short* gout = (short*)Cv + (size_t)(m0 + wm) * N + n0 + wn;
#pragma unroll
    for (int rr = 0; rr < 64; rr += 8)
      *(short8*)(gout + (size_t)(rr + orow) * N + oc8) =
          *(const short8*)(Cs + (rr + orow) * 72 + oc8);
  } else {
    // stage f32 in two 32-row passes (rows padded to 72 floats = 288B)
    float* Cf = (float*)(smem + wid * 9216);
    const int orow4 = lane >> 4, oc4 = (lane & 15) * 4;
#pragma unroll
    for (int half = 0; half < 2; half++) {
#pragma unroll
      for (int m2 = 0; m2 < 2; m2++)
#pragma unroll
        for (int n = 0; n < 4; n++)
#pragma unroll
          for (int j = 0; j < 4; j++)
            Cf[(m2 * 16 + q * 4 + j) * 72 + n * 16 + r] =
                (float)acc[half * 2 + m2][n][j] * s;
      float* gout = (float*)Cv + (size_t)(m0 + wm + half * 32) * N + n0 + wn;
#pragma unroll
      for (int rr = 0; rr < 32; rr += 4)
        *(float4*)(gout + (size_t)(rr + orow4) * N + oc4) =
            *(const float4*)(Cf + (rr + orow4) * 72 + oc4);
      __builtin_amdgcn_s_waitcnt(0);  // drain lgkm+vm before overwriting Cf next pass
    }
  }
}

extern "C" void kernel_launch(void* const* d_in, const int* in_sizes, int n_in,
                              void* d_out, int out_size, void* d_ws, size_t ws_size,
                              hipStream_t stream) {
  const float* x = (const float*)d_in[0];
  const float* lnw = (const float*)d_in[1];
  const float* lnb = (const float*)d_in[2];
  const float* w1 = (const float*)d_in[3];
  const float* w2 = (const float*)d_in[4];
  float* out = (float*)d_out;

  char* ws = (char*)d_ws;
  float* scal = (float*)ws;  // [0]=sum|w1| [1]=sum|w2| [2]=amax_x [3]=amax_h
  float* stats = (float*)(ws + OFF_STATS);
  signed char* qx = (signed char*)(ws + OFF_QX);
  signed char* qw1 = (signed char*)(ws + OFF_QW1);
  signed char* qw2 = (signed char*)(ws + OFF_QW2);
  short* hacc = (short*)(ws + OFF_HACC);
  signed char* qh = (signed char*)(ws + OFF_QX);  // reuses qx+qw1 after GEMM1

  zero_k<<<1, 64, 0, stream>>>(scal);
  abssum_k<<<2048, 256, 0, stream>>>((const float4*)w1, (DF * DM) / 4, &scal[0]);
  abssum_k<<<2048, 256, 0, stream>>>((const float4*)w2, (DM * DF) / 4, &scal[1]);
  ln_k<<<MT, 256, 0, stream>>>(x, lnw, lnb, stats, (unsigned*)&scal[2]);
  quantx_k<<<MT, 256, 0, stream>>>(x, lnw, lnb, stats, scal, qx);
  quantw_k<<<2048, 256, 0, stream>>>((const float4*)w1, &scal[0], qw1, (DF * DM) / 4);
  quantw_k<<<2048, 256, 0, stream>>>((const float4*)w2, &scal[1], qw2, (DM * DF) / 4);

  // GEMM1: M=8192, N=8192, K=2048 -> hacc int16 + amax_h
  gemm_i8<1><<<dim3((DF / 128) * (MT / 128)), 256, 0, stream>>>(qx, qw1, hacc, MT, DF, DM, DF / 128,
                                                                &scal[0], &scal[2], (unsigned*)&scal[3]);
  // stage 2 in two chunks: quantize h -> qh (int8), GEMM2 -> out
  for (int c = 0; c < MT / CH; c++) {
    quanth_k<<<2048, 256, 0, stream>>>((const short8*)(hacc + (size_t)c * CH * DF), scal,
                                       qh, (CH * DF) / 8);
    gemm_i8<0><<<dim3((DM / 128) * (CH / 128)), 256, 0, stream>>>(qh, qw2, out + (size_t)c * CH * DM,
                                                                  CH, DM, DF, DM / 128,
                                                                  &scal[1], &scal[3], nullptr);
  }
}

// Round 9
// 966.350 us; speedup vs baseline: 1.0955x; 1.0955x over previous
//
#include <hip/hip_runtime.h>

typedef signed char char8v __attribute__((ext_vector_type(8)));
typedef signed char char4v __attribute__((ext_vector_type(4)));
typedef short short8 __attribute__((ext_vector_type(8)));
typedef int int32x4 __attribute__((ext_vector_type(4)));

static constexpr int DM = 2048;   // d_model
static constexpr int DF = 8192;   // d_ff
static constexpr int MT = 8192;   // B*S tokens
static constexpr int CH = 4096;   // M-chunk for stage 2
static constexpr double INVND = 1.0 / 16777216.0;  // 1/(DF*DM), double

// workspace layout (bytes); total ~184MB
// [0,8)=sum|w1| dbl, [8,16)=sum|w2| dbl, [16,20)=amax_x f32, [20,24)=amax_h f32
static constexpr size_t OFF_STATS = 256;                           // 8192*2 f32
static constexpr size_t OFF_QX   = OFF_STATS + 65536;              // i8 [MT][DM]    16MB
static constexpr size_t OFF_QW1  = OFF_QX  + (size_t)MT * DM;      // i8 [DF][DM]    16MB
static constexpr size_t OFF_QW2  = OFF_QW1 + (size_t)DF * DM;      // i8 [DM][DF]    16MB
static constexpr size_t OFF_HACC = OFF_QW2 + (size_t)DM * DF;      // i16 [MT][DF]  128MB

__device__ __forceinline__ float waveSum(float v) {
#pragma unroll
  for (int o = 32; o > 0; o >>= 1) v += __shfl_xor(v, o, 64);
  return v;
}
__device__ __forceinline__ double waveSumD(double v) {
#pragma unroll
  for (int o = 32; o > 0; o >>= 1) v += __shfl_xor(v, o, 64);
  return v;
}
__device__ __forceinline__ float waveMax(float v) {
#pragma unroll
  for (int o = 32; o > 0; o >>= 1) v = fmaxf(v, __shfl_xor(v, o, 64));
  return v;
}
__device__ __forceinline__ float gelu_exact(float v) {
  return 0.5f * v * (1.0f + erff(v * 0.70710678118654752f));
}
__device__ __forceinline__ signed char q8(float v, float lo, float hi) {
  return (signed char)fminf(fmaxf(rintf(v), lo), hi);
}

__global__ __launch_bounds__(64) void zero_k(float* p) { p[threadIdx.x] = 0.f; }

// ---------------- sum(|w|) reduction (double accumulation -> deterministic beta) ----------------
__global__ __launch_bounds__(256) void abssum_k(const float4* __restrict__ w, int n4,
                                                double* __restrict__ out) {
  double s = 0.0;
  for (int i = blockIdx.x * 256 + threadIdx.x; i < n4; i += gridDim.x * 256) {
    float4 v = w[i];
    s += (double)fabsf(v.x) + (double)fabsf(v.y) + (double)fabsf(v.z) + (double)fabsf(v.w);
  }
  s = waveSumD(s);
  __shared__ double sm[4];
  if ((threadIdx.x & 63) == 0) sm[threadIdx.x >> 6] = s;
  __syncthreads();
  if (threadIdx.x == 0) atomicAdd(out, sm[0] + sm[1] + sm[2] + sm[3]);
}

// ---------------- layernorm stats + global absmax(x_ln) ----------------
__global__ __launch_bounds__(256) void ln_k(const float* __restrict__ x, const float* __restrict__ w,
                                            const float* __restrict__ b, float* __restrict__ stats,
                                            unsigned* __restrict__ amax) {
  __shared__ float sm[4];
  const int row = blockIdx.x, t = threadIdx.x;
  const float4* xr = (const float4*)(x + (size_t)row * DM);
  float4 v0 = xr[t], v1 = xr[t + 256];
  float s = v0.x + v0.y + v0.z + v0.w + v1.x + v1.y + v1.z + v1.w;
  s = waveSum(s);
  if ((t & 63) == 0) sm[t >> 6] = s;
  __syncthreads();
  const float mu = (sm[0] + sm[1] + sm[2] + sm[3]) * (1.0f / DM);
  __syncthreads();
  float d[8] = {v0.x - mu, v0.y - mu, v0.z - mu, v0.w - mu,
                v1.x - mu, v1.y - mu, v1.z - mu, v1.w - mu};
  float sq = 0.f;
#pragma unroll
  for (int i = 0; i < 8; i++) sq += d[i] * d[i];
  sq = waveSum(sq);
  if ((t & 63) == 0) sm[t >> 6] = sq;
  __syncthreads();
  const float var = (sm[0] + sm[1] + sm[2] + sm[3]) * (1.0f / DM);
  const float rstd = 1.0f / sqrtf(var + 1e-5f);
  __syncthreads();
  const float4* wr = (const float4*)w;
  const float4* br = (const float4*)b;
  float4 w0 = wr[t], w1v = wr[t + 256], b0 = br[t], b1v = br[t + 256];
  float m = 0.f;
  m = fmaxf(m, fabsf(d[0] * rstd * w0.x + b0.x));
  m = fmaxf(m, fabsf(d[1] * rstd * w0.y + b0.y));
  m = fmaxf(m, fabsf(d[2] * rstd * w0.z + b0.z));
  m = fmaxf(m, fabsf(d[3] * rstd * w0.w + b0.w));
  m = fmaxf(m, fabsf(d[4] * rstd * w1v.x + b1v.x));
  m = fmaxf(m, fabsf(d[5] * rstd * w1v.y + b1v.y));
  m = fmaxf(m, fabsf(d[6] * rstd * w1v.z + b1v.z));
  m = fmaxf(m, fabsf(d[7] * rstd * w1v.w + b1v.w));
  m = waveMax(m);
  if ((t & 63) == 0) sm[t >> 6] = m;
  __syncthreads();
  if (t == 0) {
    float mm = fmaxf(fmaxf(sm[0], sm[1]), fmaxf(sm[2], sm[3]));
    stats[2 * row] = mu;
    stats[2 * row + 1] = rstd;
    atomicMax(amax, __float_as_uint(mm));
  }
}

// ---------------- quantize activations -> int8 ----------------
__global__ __launch_bounds__(256) void quantx_k(const float* __restrict__ x, const float* __restrict__ w,
                                                const float* __restrict__ b, const float* __restrict__ stats,
                                                const float* __restrict__ fam, signed char* __restrict__ qx) {
  const int row = blockIdx.x, t = threadIdx.x;
  const float mu = stats[2 * row], rstd = stats[2 * row + 1];
  const float sc = 127.0f / fmaxf(fam[0], 1e-5f);
  const float4* xr = (const float4*)(x + (size_t)row * DM);
  const float4* wr = (const float4*)w;
  const float4* br = (const float4*)b;
  float4 v0 = xr[2 * t], v1 = xr[2 * t + 1];
  float4 w0 = wr[2 * t], w1v = wr[2 * t + 1];
  float4 b0 = br[2 * t], b1v = br[2 * t + 1];
  char8v o;
  o[0] = q8(((v0.x - mu) * rstd * w0.x + b0.x) * sc, -127.f, 127.f);
  o[1] = q8(((v0.y - mu) * rstd * w0.y + b0.y) * sc, -127.f, 127.f);
  o[2] = q8(((v0.z - mu) * rstd * w0.z + b0.z) * sc, -127.f, 127.f);
  o[3] = q8(((v0.w - mu) * rstd * w0.w + b0.w) * sc, -127.f, 127.f);
  o[4] = q8(((v1.x - mu) * rstd * w1v.x + b1v.x) * sc, -127.f, 127.f);
  o[5] = q8(((v1.y - mu) * rstd * w1v.y + b1v.y) * sc, -127.f, 127.f);
  o[6] = q8(((v1.z - mu) * rstd * w1v.z + b1v.z) * sc, -127.f, 127.f);
  o[7] = q8(((v1.w - mu) * rstd * w1v.w + b1v.w) * sc, -127.f, 127.f);
  *(char8v*)(qx + (size_t)row * DM + t * 8) = o;
}

// ---------------- ternarize weights -> int8 ----------------
__global__ __launch_bounds__(256) void quantw_k(const float4* __restrict__ w,
                                                const double* __restrict__ sumabs,
                                                signed char* __restrict__ qw, int n4) {
  const float beta = fmaxf((float)(sumabs[0] * INVND), 1e-5f);
  const float rb = 1.0f / beta;
  for (int i = blockIdx.x * 256 + threadIdx.x; i < n4; i += gridDim.x * 256) {
    float4 v = w[i];
    char4v o;
    o[0] = q8(v.x * rb, -1.f, 1.f);
    o[1] = q8(v.y * rb, -1.f, 1.f);
    o[2] = q8(v.z * rb, -1.f, 1.f);
    o[3] = q8(v.w * rb, -1.f, 1.f);
    *(char4v*)(qw + (size_t)i * 4) = o;
  }
}

// ---------------- quantize h chunk: gelu(s1*acc) -> int8 ----------------
__global__ __launch_bounds__(256) void quanth_k(const short8* __restrict__ hacc,
                                                const double* __restrict__ dsum,
                                                const float* __restrict__ fam,
                                                signed char* __restrict__ qh, int n8) {
  const float beta = fmaxf((float)(dsum[0] * INVND), 1e-5f);
  const float s1 = beta * fmaxf(fam[0], 1e-5f) * (1.0f / 127.0f);
  const float sc2 = 127.0f / fmaxf(fam[1], 1e-5f);
  for (int i = blockIdx.x * 256 + threadIdx.x; i < n8; i += gridDim.x * 256) {
    short8 v = hacc[i];
    char8v o;
#pragma unroll
    for (int j = 0; j < 8; j++) {
      const float g = gelu_exact((float)v[j] * s1);
      o[j] = q8(g * sc2, -127.f, 127.f);
    }
    *(char8v*)(qh + (size_t)i * 8) = o;
  }
}

// ---------------- GEMM: C[M][N] = A[M][K] * B[N][K]^T, exact int8 MFMA ----------------
// EPI=1: store raw acc as int16 + amax(gelu(acc*s)); EPI=0: store f32 acc*s
__device__ __forceinline__ void gll16(const signed char* g, signed char* l) {
  __builtin_amdgcn_global_load_lds((const __attribute__((address_space(1))) void*)g,
                                   (__attribute__((address_space(3))) void*)l, 16, 0, 0);
}

template <int EPI>
__global__ __launch_bounds__(256, 4) void gemm_i8(const signed char* __restrict__ A,
                                                  const signed char* __restrict__ B,
                                                  void* __restrict__ Cv, int M, int N, int K,
                                                  int bandrows,
                                                  const double* __restrict__ p_sumw,
                                                  const float* __restrict__ p_amax,
                                                  unsigned* __restrict__ amax_out) {
  __shared__ signed char As[128 * 64];  // 8KB, BK=64 bytes
  __shared__ signed char Bs[128 * 64];
  const int tid = threadIdx.x;
  const int wid = tid >> 6, lane = tid & 63;

  // L2-blocked band decomposition: XCD (= bid&7) owns 'bandrows' contiguous tile-rows,
  // traversed column-major so the A-band stays L2-resident and each B-column is read once.
  const int xcd = (int)blockIdx.x & 7;
  const int idx = (int)blockIdx.x >> 3;
  const int by = xcd * bandrows + (idx % bandrows);
  const int bx = idx / bandrows;
  const int m0 = by * 128, n0 = bx * 128;
  const int wm = (wid >> 1) * 64, wn = (wid & 1) * 64;

  int32x4 acc[4][4];
#pragma unroll
  for (int i = 0; i < 4; i++)
#pragma unroll
    for (int j = 0; j < 4; j++) acc[i][j] = int32x4{0, 0, 0, 0};

  // staging: thread t -> row t/4 (+64 on 2nd issue), byte-col (t&3)*16
  const int srow = tid >> 2;
  const int scol = (tid & 3) * 16;
  const signed char* gA = A + (size_t)(m0 + srow) * K + scol;
  const signed char* gB = B + (size_t)(n0 + srow) * K + scol;
  const size_t rowK64 = (size_t)64 * K;

  // fragment LDS byte offsets: lane = 16q + r -> row r, k-bytes [16q,16q+16)
  const int lrow = lane & 15;
  const int lkb = (lane >> 4) * 16;
  const int aoff = (wm + lrow) * 64 + lkb;
  const int boff = (wn + lrow) * 64 + lkb;

  for (int k0 = 0; k0 < K; k0 += 64) {
    __syncthreads();
    gll16(gA + k0,          As + wid * 1024);
    gll16(gA + k0 + rowK64, As + 4096 + wid * 1024);
    gll16(gB + k0,          Bs + wid * 1024);
    gll16(gB + k0 + rowK64, Bs + 4096 + wid * 1024);
    __syncthreads();

    int32x4 af[4], bfv[4];
#pragma unroll
    for (int m = 0; m < 4; m++) af[m] = *(const int32x4*)(As + aoff + m * 1024);
#pragma unroll
    for (int n = 0; n < 4; n++) bfv[n] = *(const int32x4*)(Bs + boff + n * 1024);
#pragma unroll
    for (int m = 0; m < 4; m++)
#pragma unroll
      for (int n = 0; n < 4; n++)
        acc[m][n] = __builtin_amdgcn_mfma_i32_16x16x64_i8(af[m], bfv[n], acc[m][n], 0, 0, 0);
  }

  const float beta = fmaxf((float)(p_sumw[0] * INVND), 1e-5f);
  const float s = beta * fmaxf(p_amax[0], 1e-5f) * (1.0f / 127.0f);
  const int crow0 = m0 + wm + ((lane >> 4) << 2);
  const int ccol0 = n0 + wn + (lane & 15);
  float lmax = 0.f;
#pragma unroll
  for (int m = 0; m < 4; m++) {
#pragma unroll
    for (int n = 0; n < 4; n++) {
#pragma unroll
      for (int j = 0; j < 4; j++) {
        const float a = (float)acc[m][n][j];  // exact integer
        const size_t idx2 = (size_t)(crow0 + m * 16 + j) * N + (ccol0 + n * 16);
        if (EPI == 1) {
          ((short*)Cv)[idx2] = (short)fminf(fmaxf(a, -32767.f), 32767.f);
          lmax = fmaxf(lmax, fabsf(gelu_exact(a * s)));
        } else {
          ((float*)Cv)[idx2] = a * s;
        }
      }
    }
  }
  if (EPI == 1) {
    lmax = waveMax(lmax);
    if (lane == 0) atomicMax(amax_out, __float_as_uint(lmax));
  }
}

extern "C" void kernel_launch(void* const* d_in, const int* in_sizes, int n_in,
                              void* d_out, int out_size, void* d_ws, size_t ws_size,
                              hipStream_t stream) {
  const float* x = (const float*)d_in[0];
  const float* lnw = (const float*)d_in[1];
  const float* lnb = (const float*)d_in[2];
  const float* w1 = (const float*)d_in[3];
  const float* w2 = (const float*)d_in[4];
  float* out = (float*)d_out;

  char* ws = (char*)d_ws;
  double* dsum = (double*)ws;             // [0]=sum|w1| [1]=sum|w2|
  float* fam = (float*)(ws + 16);         // [0]=amax_x [1]=amax_h
  float* stats = (float*)(ws + OFF_STATS);
  signed char* qx = (signed char*)(ws + OFF_QX);
  signed char* qw1 = (signed char*)(ws + OFF_QW1);
  signed char* qw2 = (signed char*)(ws + OFF_QW2);
  short* hacc = (short*)(ws + OFF_HACC);
  signed char* qh = (signed char*)(ws + OFF_QX);  // reuses qx+qw1 after GEMM1

  zero_k<<<1, 64, 0, stream>>>((float*)ws);
  abssum_k<<<2048, 256, 0, stream>>>((const float4*)w1, (DF * DM) / 4, &dsum[0]);
  abssum_k<<<2048, 256, 0, stream>>>((const float4*)w2, (DM * DF) / 4, &dsum[1]);
  ln_k<<<MT, 256, 0, stream>>>(x, lnw, lnb, stats, (unsigned*)&fam[0]);
  quantx_k<<<MT, 256, 0, stream>>>(x, lnw, lnb, stats, fam, qx);
  quantw_k<<<2048, 256, 0, stream>>>((const float4*)w1, &dsum[0], qw1, (DF * DM) / 4);
  quantw_k<<<2048, 256, 0, stream>>>((const float4*)w2, &dsum[1], qw2, (DM * DF) / 4);

  // GEMM1: M=8192, N=8192, K=2048 -> hacc int16 + amax_h. bands: 64 tile-rows / 8 XCDs = 8
  gemm_i8<1><<<dim3((DF / 128) * (MT / 128)), 256, 0, stream>>>(qx, qw1, hacc, MT, DF, DM,
                                                                MT / 128 / 8, &dsum[0], &fam[0],
                                                                (unsigned*)&fam[1]);
  // stage 2 in two chunks: quantize h -> qh (int8), GEMM2 -> out. bands: 32/8 = 4
  for (int c = 0; c < MT / CH; c++) {
    quanth_k<<<2048, 256, 0, stream>>>((const short8*)(hacc + (size_t)c * CH * DF), &dsum[0], fam,
                                       qh, (CH * DF) / 8);
    gemm_i8<0><<<dim3((DM / 128) * (CH / 128)), 256, 0, stream>>>(qh, qw2, out + (size_t)c * CH * DM,
                                                                  CH, DM, DF, CH / 128 / 8,
                                                                  &dsum[1], &fam[1], nullptr);
  }
}